// Round 1
// 355.368 us; speedup vs baseline: 1.1005x; 1.1005x over previous
//
#include <hip/hip_runtime.h>
#include <math.h>

// Problem constants
#define NROWS 16384   // 32*512
#define H     768
#define KEXP  6912    // 768 (silu*base_w) + 768*8 (bases*spline_w*scaler)
#define NCHUNK 108    // KEXP/64 K-steps
#define NITER 54      // 2 K-steps per 8-phase iteration

typedef __attribute__((ext_vector_type(8))) short  bhalf8;
typedef __attribute__((ext_vector_type(4))) float  floatx4;

__device__ __forceinline__ unsigned short f2bf(float f) {
    unsigned int u = __float_as_uint(f);
    u = (u + 0x7FFFu + ((u >> 16) & 1u)) >> 16;   // RNE
    return (unsigned short)u;
}
__device__ __forceinline__ float bf2f(unsigned short h) {
    return __uint_as_float(((unsigned int)h) << 16);
}
__device__ __forceinline__ unsigned int pack2(unsigned short a, unsigned short b) {
    return (unsigned int)a | ((unsigned int)b << 16);
}
__device__ __forceinline__ float silu_f(float x) { return x / (1.0f + __expf(-x)); }

// Branch-free tanh-form GELU (|err vs exact erf-GELU| < ~1e-3 in u)
__device__ __forceinline__ float gelu_fast(float x) {
    float x3 = x * x * x;
    float y = fmaf(x3, 0.0356774081f, x * 0.7978845608f);
    float e = __expf(2.0f * y);
    float th = 1.0f - 2.0f / (e + 1.0f);
    return 0.5f * x * (1.0f + th);
}

// Closed-form cubic B-spline bases on uniform knots g[j] = (j-3)*0.4 - 1.
__device__ __forceinline__ void kan_bases(float x, float* __restrict__ b) {
    const float c6 = 0.166666666667f;
    float u  = fmaf(x, 2.5f, 5.5f);
    float fj = floorf(u);
    float t  = u - fj;
    int  j0  = (int)fj;
    float t2 = t * t, t3 = t2 * t;
    float n0 = t3 * c6;
    float n1 = fmaf(t3, -0.5f, fmaf(t2, 0.5f, fmaf(t, 0.5f, c6)));
    float n2 = fmaf(t3, 0.5f, fmaf(t2, -1.0f, 0.666666666667f));
    float omt = 1.0f - t;
    float n3 = omt * omt * omt * c6;
#pragma unroll
    for (int c = 0; c < 8; ++c) {
        int d = j0 - c;
        float v = (d == 0) ? n0 : 0.0f;
        v = (d == 1) ? n1 : v;
        v = (d == 2) ? n2 : v;
        v = (d == 3) ? n3 : v;
        b[c] = v;
    }
}

// ---- Merged prep: W' bf16 [768][6912] (blocks 0..767) and
//      F bf16 [16384][6912] (blocks 768..17151). (unchanged)
__global__ __launch_bounds__(256) void prep_expand(
    const float* __restrict__ x, const float* __restrict__ bw,
    const float* __restrict__ sw, const float* __restrict__ sc,
    unsigned short* __restrict__ wp, unsigned short* __restrict__ F)
{
    const int b = blockIdx.x, t = threadIdx.x;
    if (b < H) {
        const int n = b;
        const float* bwr = bw + (size_t)n * H;
        unsigned short* out = wp + (size_t)n * KEXP;
        if (t < 96) {
            const float4* xp = (const float4*)(bwr + t * 8);
            float4 v0 = xp[0], v1 = xp[1];
            uint4 pk;
            pk.x = pack2(f2bf(v0.x), f2bf(v0.y));
            pk.y = pack2(f2bf(v0.z), f2bf(v0.w));
            pk.z = pack2(f2bf(v1.x), f2bf(v1.y));
            pk.w = pack2(f2bf(v1.z), f2bf(v1.w));
            *(uint4*)(out + t * 8) = pk;
        }
#pragma unroll
        for (int p = 0; p < 3; ++p) {
            int i = t + p * 256;
            float s = sc[(size_t)n * H + i];
            const float4* swp = (const float4*)(sw + ((size_t)n * H + i) * 8);
            float4 w0 = swp[0], w1 = swp[1];
            uint4 pk;
            pk.x = pack2(f2bf(w0.x * s), f2bf(w0.y * s));
            pk.y = pack2(f2bf(w0.z * s), f2bf(w0.w * s));
            pk.z = pack2(f2bf(w1.x * s), f2bf(w1.y * s));
            pk.w = pack2(f2bf(w1.z * s), f2bf(w1.w * s));
            *(uint4*)(out + H + (size_t)i * 8) = pk;
        }
    } else {
        const int n = b - H;
        __shared__ float sX[H];
        const float* xr = x + (size_t)n * H;
        if (t < 192) ((float4*)sX)[t] = ((const float4*)xr)[t];
        __syncthreads();
        unsigned short* out = F + (size_t)n * KEXP;
        if (t < 96) {
            const float4* xp = (const float4*)(sX + t * 8);
            float4 v0 = xp[0], v1 = xp[1];
            uint4 pk;
            pk.x = pack2(f2bf(silu_f(v0.x)), f2bf(silu_f(v0.y)));
            pk.y = pack2(f2bf(silu_f(v0.z)), f2bf(silu_f(v0.w)));
            pk.z = pack2(f2bf(silu_f(v1.x)), f2bf(silu_f(v1.y)));
            pk.w = pack2(f2bf(silu_f(v1.z)), f2bf(silu_f(v1.w)));
            *(uint4*)(out + t * 8) = pk;
        }
#pragma unroll
        for (int p = 0; p < 3; ++p) {
            int i = t + p * 256;
            float xv = sX[i];
            float bb[8];
            kan_bases(xv, bb);
            uint4 pk;
            pk.x = pack2(f2bf(bb[0]), f2bf(bb[1]));
            pk.y = pack2(f2bf(bb[2]), f2bf(bb[3]));
            pk.z = pack2(f2bf(bb[4]), f2bf(bb[5]));
            pk.w = pack2(f2bf(bb[6]), f2bf(bb[7]));
            *(uint4*)(out + H + (size_t)i * 8) = pk;
        }
    }
}

// ==== Layer 1: 256x256 8-phase bf16 GEMM (T1+T2-equiv+T3+T4+T5 port) ====
//
// M=16384, N=768, K=6912. Grid = 64 rowT x 3 colT = 192 blocks, 512 thr (8 waves, 2Mx4N).
// Each phase = one 128x128 C-quadrant: touches exactly ONE A-half + ONE B-half of LDS.
// Quadrant order (0,0)->(1,0)->(1,1)->(0,1); per K-step each half's LAST read:
//   A0:P4  A1:P3  B0:P2  B1:P4   (same +4 for the buf1 K-step)
// One half-tile stage per phase (2x global_load_lds, 16B), targets:
//   P1:A0(k+1)->buf1  P2:B1(k+1)->buf1  P3:B0(k+2)->buf0  P4:A1(k+2)->buf0
//   P5:A0(k+2)->buf0  P6:B1(k+2)->buf0  P7:B0(k+3)->buf1  P8:A1(k+3)->buf1
// Every stage is >=1 barrier after that region's last read (race-free), and
// s_waitcnt vmcnt(4) at P4/P8 covers every issue->first-read deadline with
// in-order retirement (2 halves = 4 loads stay in flight; never vmcnt(0) in loop).
// LDS granule swizzle: slot ^= (row&7) on BOTH the gload source and ds_read side
// (the current kernel's measured-0-conflict scheme, kept verbatim).

#define AS1 __attribute__((address_space(1)))
#define AS3 __attribute__((address_space(3)))

#define DSR(D, A, O) asm volatile("ds_read_b128 %0, %1 offset:" #O : "=v"(D) : "v"(A) : "memory")
#define LDA(O) do{ DSR(fA[0],avA[0],O); DSR(fA[1],avA[1],O); DSR(fA[2],avA[2],O); DSR(fA[3],avA[3],O); \
                   DSR(fA[4],avA[4],O); DSR(fA[5],avA[5],O); DSR(fA[6],avA[6],O); DSR(fA[7],avA[7],O); }while(0)
#define LDB(O) do{ DSR(fB[0],avB[0],O); DSR(fB[1],avB[1],O); DSR(fB[2],avB[2],O); DSR(fB[3],avB[3],O); }while(0)

#define MM(QM,QN) do{ \
    _Pragma("unroll") \
    for (int kk = 0; kk < 2; ++kk) \
        _Pragma("unroll") \
        for (int im = 0; im < 4; ++im) \
            _Pragma("unroll") \
            for (int in_ = 0; in_ < 2; ++in_) \
                acc[QM][QN][im][in_] = __builtin_amdgcn_mfma_f32_16x16x32_bf16( \
                    fA[im*2+kk], fB[in_*2+kk], acc[QM][QN][im][in_], 0, 0, 0); \
}while(0)

#define STG_A(BF,HH,KS) do{ \
    __builtin_amdgcn_global_load_lds((const AS1 void*)(pA##HH[0] + (size_t)(KS)*64), \
        (AS3 void*)&sA[BF][HH][wb8], 16, 0, 0); \
    __builtin_amdgcn_global_load_lds((const AS1 void*)(pA##HH[1] + (size_t)(KS)*64), \
        (AS3 void*)&sA[BF][HH][4096 + wb8], 16, 0, 0); \
}while(0)
#define STG_B(BF,HH,KS) do{ \
    __builtin_amdgcn_global_load_lds((const AS1 void*)(pB##HH[0] + (size_t)(KS)*64), \
        (AS3 void*)&sB[BF][HH][wb8], 16, 0, 0); \
    __builtin_amdgcn_global_load_lds((const AS1 void*)(pB##HH[1] + (size_t)(KS)*64), \
        (AS3 void*)&sB[BF][HH][4096 + wb8], 16, 0, 0); \
}while(0)

#define PH_MID do{ __builtin_amdgcn_s_barrier(); \
    asm volatile("s_waitcnt lgkmcnt(0)" ::: "memory"); \
    __builtin_amdgcn_sched_barrier(0); \
    __builtin_amdgcn_s_setprio(1); }while(0)
#define PH_END do{ __builtin_amdgcn_s_setprio(0); \
    __builtin_amdgcn_sched_barrier(0); \
    __builtin_amdgcn_s_barrier(); }while(0)
#define PH_END_VMN(N) do{ __builtin_amdgcn_s_setprio(0); \
    __builtin_amdgcn_sched_barrier(0); \
    asm volatile("s_waitcnt vmcnt(" #N ")" ::: "memory"); \
    __builtin_amdgcn_s_barrier(); }while(0)

__global__ __launch_bounds__(512, 2) void kan1_gemm(
    const unsigned short* __restrict__ F, const unsigned short* __restrict__ wp,
    unsigned short* __restrict__ l1)
{
    __shared__ __align__(16) unsigned short sA[2][2][8192];  // [buf][half][128*64]
    __shared__ __align__(16) unsigned short sB[2][2][8192];

    const int b = blockIdx.x;                 // 0..191
    const int swz = (b & 7) * 24 + (b >> 3);  // bijective: 192 % 8 == 0
    const int rowT = swz / 3, colT = swz - rowT * 3;  // 8 rowT x 3 colT per XCD
    const int rowBase = rowT * 256, colBase = colT * 256;

    const int t = threadIdx.x;
    const int lane = t & 63;
    const int quad = lane >> 4, lm = lane & 15, p7 = lane & 7;
    const int wv = t >> 6, wr = wv & 1, wc = wv >> 1;   // 2M x 4N wave grid

    // staging geometry: granule g = p*512 + t; row r = p*64 + (t>>3); slot = (t&7)^(r&7)
    const int rr = t >> 3;
    const int slotx = (t & 7) ^ (rr & 7);
    const int wb8 = (t & 448) * 8;            // wave-uniform LDS element base (granule wv*64)

    const unsigned short* pA0[2]; const unsigned short* pA1[2];
    const unsigned short* pB0[2]; const unsigned short* pB1[2];
#pragma unroll
    for (int p = 0; p < 2; ++p) {
        pA0[p] = F  + (size_t)(rowBase +       p*64 + rr) * KEXP + slotx*8;
        pA1[p] = F  + (size_t)(rowBase + 128 + p*64 + rr) * KEXP + slotx*8;
        pB0[p] = wp + (size_t)(colBase +       p*64 + rr) * KEXP + slotx*8;
        pB1[p] = wp + (size_t)(colBase + 128 + p*64 + rr) * KEXP + slotx*8;
    }

    // ds_read addresses (byte, incl. LDS base); buf/half selected via asm offset imm
    unsigned int avA[8], avB[4];
    {
        unsigned int aB = (unsigned int)(size_t)(AS3 unsigned short*)&sA[0][0][0];
        unsigned int bB = (unsigned int)(size_t)(AS3 unsigned short*)&sB[0][0][0];
#pragma unroll
        for (int im = 0; im < 4; ++im)
#pragma unroll
            for (int kk = 0; kk < 2; ++kk)
                avA[im*2+kk] = aB + (unsigned)(((wr*64 + im*16 + lm)*64 + (((kk*4+quad)^p7)*8)) * 2);
#pragma unroll
        for (int in_ = 0; in_ < 2; ++in_)
#pragma unroll
            for (int kk = 0; kk < 2; ++kk)
                avB[in_*2+kk] = bB + (unsigned)(((wc*32 + in_*16 + lm)*64 + (((kk*4+quad)^p7)*8)) * 2);
    }

    floatx4 acc[2][2][4][2] = {};   // [qm][qn][im][in] -> 128 VGPR
    bhalf8 fA[8], fB[4];

    // prologue: buf0 <- ks0 (4 halves), buf1 <- B0(1), A1(1); leave those 2 in flight
    STG_A(0,0,0); STG_A(0,1,0); STG_B(0,0,0); STG_B(0,1,0);
    STG_B(1,0,1); STG_A(1,1,1);
    asm volatile("s_waitcnt vmcnt(4)" ::: "memory");
    __builtin_amdgcn_s_barrier();

#pragma unroll 1
    for (int i = 0; i < NITER - 1; ++i) {
        const int b1 = 2*i + 1, nx = 2*i + 2, nb = 2*i + 3;
        // K-step 2i from buf0 (A offsets 0/16384, B same), quadrants (0,0)(1,0)(1,1)(0,1)
        LDA(0);     LDB(0);     STG_A(1,0,b1); PH_MID; MM(0,0); PH_END;
        LDA(16384);             STG_B(1,1,b1); PH_MID; MM(1,0); PH_END;
        LDB(16384);             STG_B(0,0,nx); PH_MID; MM(1,1); PH_END;
        LDA(0);                 STG_A(0,1,nx); PH_MID; MM(0,1); PH_END_VMN(4);
        // K-step 2i+1 from buf1 (offsets 32768/49152)
        LDA(32768); LDB(32768); STG_A(0,0,nx); PH_MID; MM(0,0); PH_END;
        LDA(49152);             STG_B(0,1,nx); PH_MID; MM(1,0); PH_END;
        LDB(49152);             STG_B(1,0,nb); PH_MID; MM(1,1); PH_END;
        LDA(32768);             STG_A(1,1,nb); PH_MID; MM(0,1); PH_END_VMN(4);
    }
    // peeled last iteration (ks 106,107): only the two still-needed stages; drain at P4
    LDA(0);     LDB(0);     STG_A(1,0,107); PH_MID; MM(0,0); PH_END;
    LDA(16384);             STG_B(1,1,107); PH_MID; MM(1,0); PH_END;
    LDB(16384);                             PH_MID; MM(1,1); PH_END;
    LDA(0);                                 PH_MID; MM(0,1); PH_END_VMN(0);
    LDA(32768); LDB(32768);                 PH_MID; MM(0,0); PH_END;
    LDA(49152);                             PH_MID; MM(1,0); PH_END;
    LDB(49152);                             PH_MID; MM(1,1); PH_END;
    LDA(32768);                             PH_MID; MM(0,1); PH_END;

    // epilogue: C layout col=lane&15, row=quad*4+reg (dtype-independent, verified)
#pragma unroll
    for (int qm = 0; qm < 2; ++qm)
#pragma unroll
    for (int qn = 0; qn < 2; ++qn)
#pragma unroll
    for (int im = 0; im < 4; ++im)
#pragma unroll
    for (int in_ = 0; in_ < 2; ++in_) {
        const int row0 = rowBase + qm*128 + wr*64 + im*16 + quad*4;
        const int col  = colBase + qn*128 + wc*32 + in_*16 + lm;
#pragma unroll
        for (int rg = 0; rg < 4; ++rg)
            l1[(size_t)(row0 + rg) * H + col] = f2bf(acc[qm][qn][im][in_][rg]);
    }
}

// ---- Layer 2: unchanged (R5 shape: 4 rows/block, wave per row)
__global__ __launch_bounds__(256) void kan2_kernel(
    const unsigned short* __restrict__ l1, const float* __restrict__ bw,
    const float* __restrict__ sw, const float* __restrict__ sc,
    float* __restrict__ out)
{
    const int lane = threadIdx.x & 63;
    const int wv = threadIdx.x >> 6;
    const int n = blockIdx.x * 4 + wv;
    float a0 = 0.f, a1 = 0.f;
#pragma unroll
    for (int ii = 0; ii < H / 64; ++ii) {
        int i = lane + ii * 64;
        float h = bf2f(l1[(size_t)n * H + i]);
        float u = gelu_fast(h);
        float f0 = silu_f(u);
        float bb[8];
        kan_bases(u, bb);
        float bw0 = bw[i], bw1 = bw[H + i];
        float s0 = sc[i], s1 = sc[H + i];
        const float4* q0 = (const float4*)(sw + (size_t)i * 8);
        const float4* q1 = (const float4*)(sw + (size_t)(H + i) * 8);
        float4 w00 = q0[0], w01 = q0[1];
        float4 w10 = q1[0], w11 = q1[1];
        float t0 = bb[0]*w00.x + bb[1]*w00.y + bb[2]*w00.z + bb[3]*w00.w
                 + bb[4]*w01.x + bb[5]*w01.y + bb[6]*w01.z + bb[7]*w01.w;
        float t1 = bb[0]*w10.x + bb[1]*w10.y + bb[2]*w10.z + bb[3]*w10.w
                 + bb[4]*w11.x + bb[5]*w11.y + bb[6]*w11.z + bb[7]*w11.w;
        a0 += f0 * bw0 + s0 * t0;
        a1 += f0 * bw1 + s1 * t1;
    }
#pragma unroll
    for (int off = 32; off > 0; off >>= 1) {
        a0 += __shfl_down(a0, off, 64);
        a1 += __shfl_down(a1, off, 64);
    }
    if (lane == 0) {
        out[(size_t)n * 2 + 0] = a0;
        out[(size_t)n * 2 + 1] = a1;
    }
}

extern "C" void kernel_launch(void* const* d_in, const int* in_sizes, int n_in,
                              void* d_out, int out_size, void* d_ws, size_t ws_size,
                              hipStream_t stream) {
    const float* hidden = (const float*)d_in[0];
    const float* bw1    = (const float*)d_in[1];
    const float* sw1    = (const float*)d_in[2];
    const float* sc1    = (const float*)d_in[3];
    const float* bw2    = (const float*)d_in[4];
    const float* sw2    = (const float*)d_in[5];
    const float* sc2    = (const float*)d_in[6];
    float* out = (float*)d_out;

    const size_t l1_elems = (size_t)NROWS * H;     // 25.2 MB bf16
    const size_t wp_elems = (size_t)H * KEXP;      // 10.6 MB bf16
    unsigned short* l1 = (unsigned short*)d_ws;
    unsigned short* wp = l1 + l1_elems;
    unsigned short* F  = wp + wp_elems;            // 226.5 MB bf16

    prep_expand<<<H + NROWS, 256, 0, stream>>>(hidden, bw1, sw1, sc1, wp, F);
    kan1_gemm<<<192, 512, 0, stream>>>(F, wp, l1);
    kan2_kernel<<<NROWS / 4, 256, 0, stream>>>(l1, bw2, sw2, sc2, out);
}

// Round 2
// 336.355 us; speedup vs baseline: 1.1627x; 1.0565x over previous
//
#include <hip/hip_runtime.h>
#include <math.h>

// Problem constants
#define NROWS 16384   // 32*512
#define H     768
#define KEXP  6912    // 768 (silu*base_w) + 768*8 (bases*spline_w*scaler)
#define NCHUNK 108    // KEXP/64 K-steps
#define NITER 54      // 2 K-steps per 8-phase iteration

typedef __attribute__((ext_vector_type(8))) short  bhalf8;
typedef __attribute__((ext_vector_type(4))) float  floatx4;

__device__ __forceinline__ unsigned short f2bf(float f) {
    unsigned int u = __float_as_uint(f);
    u = (u + 0x7FFFu + ((u >> 16) & 1u)) >> 16;   // RNE
    return (unsigned short)u;
}
__device__ __forceinline__ float bf2f(unsigned short h) {
    return __uint_as_float(((unsigned int)h) << 16);
}
__device__ __forceinline__ unsigned int pack2(unsigned short a, unsigned short b) {
    return (unsigned int)a | ((unsigned int)b << 16);
}
__device__ __forceinline__ float silu_f(float x) { return x / (1.0f + __expf(-x)); }

// Branch-free tanh-form GELU (|err vs exact erf-GELU| < ~1e-3 in u)
__device__ __forceinline__ float gelu_fast(float x) {
    float x3 = x * x * x;
    float y = fmaf(x3, 0.0356774081f, x * 0.7978845608f);
    float e = __expf(2.0f * y);
    float th = 1.0f - 2.0f / (e + 1.0f);
    return 0.5f * x * (1.0f + th);
}

// Closed-form cubic B-spline bases on uniform knots g[j] = (j-3)*0.4 - 1.
__device__ __forceinline__ void kan_bases(float x, float* __restrict__ b) {
    const float c6 = 0.166666666667f;
    float u  = fmaf(x, 2.5f, 5.5f);
    float fj = floorf(u);
    float t  = u - fj;
    int  j0  = (int)fj;
    float t2 = t * t, t3 = t2 * t;
    float n0 = t3 * c6;
    float n1 = fmaf(t3, -0.5f, fmaf(t2, 0.5f, fmaf(t, 0.5f, c6)));
    float n2 = fmaf(t3, 0.5f, fmaf(t2, -1.0f, 0.666666666667f));
    float omt = 1.0f - t;
    float n3 = omt * omt * omt * c6;
#pragma unroll
    for (int c = 0; c < 8; ++c) {
        int d = j0 - c;
        float v = (d == 0) ? n0 : 0.0f;
        v = (d == 1) ? n1 : v;
        v = (d == 2) ? n2 : v;
        v = (d == 3) ? n3 : v;
        b[c] = v;
    }
}

// ---- Merged prep: W' bf16 [768][6912] (blocks 0..767) and
//      F bf16 [16384][6912] (blocks 768..17151). (unchanged)
__global__ __launch_bounds__(256) void prep_expand(
    const float* __restrict__ x, const float* __restrict__ bw,
    const float* __restrict__ sw, const float* __restrict__ sc,
    unsigned short* __restrict__ wp, unsigned short* __restrict__ F)
{
    const int b = blockIdx.x, t = threadIdx.x;
    if (b < H) {
        const int n = b;
        const float* bwr = bw + (size_t)n * H;
        unsigned short* out = wp + (size_t)n * KEXP;
        if (t < 96) {
            const float4* xp = (const float4*)(bwr + t * 8);
            float4 v0 = xp[0], v1 = xp[1];
            uint4 pk;
            pk.x = pack2(f2bf(v0.x), f2bf(v0.y));
            pk.y = pack2(f2bf(v0.z), f2bf(v0.w));
            pk.z = pack2(f2bf(v1.x), f2bf(v1.y));
            pk.w = pack2(f2bf(v1.z), f2bf(v1.w));
            *(uint4*)(out + t * 8) = pk;
        }
#pragma unroll
        for (int p = 0; p < 3; ++p) {
            int i = t + p * 256;
            float s = sc[(size_t)n * H + i];
            const float4* swp = (const float4*)(sw + ((size_t)n * H + i) * 8);
            float4 w0 = swp[0], w1 = swp[1];
            uint4 pk;
            pk.x = pack2(f2bf(w0.x * s), f2bf(w0.y * s));
            pk.y = pack2(f2bf(w0.z * s), f2bf(w0.w * s));
            pk.z = pack2(f2bf(w1.x * s), f2bf(w1.y * s));
            pk.w = pack2(f2bf(w1.z * s), f2bf(w1.w * s));
            *(uint4*)(out + H + (size_t)i * 8) = pk;
        }
    } else {
        const int n = b - H;
        __shared__ float sX[H];
        const float* xr = x + (size_t)n * H;
        if (t < 192) ((float4*)sX)[t] = ((const float4*)xr)[t];
        __syncthreads();
        unsigned short* out = F + (size_t)n * KEXP;
        if (t < 96) {
            const float4* xp = (const float4*)(sX + t * 8);
            float4 v0 = xp[0], v1 = xp[1];
            uint4 pk;
            pk.x = pack2(f2bf(silu_f(v0.x)), f2bf(silu_f(v0.y)));
            pk.y = pack2(f2bf(silu_f(v0.z)), f2bf(silu_f(v0.w)));
            pk.z = pack2(f2bf(silu_f(v1.x)), f2bf(silu_f(v1.y)));
            pk.w = pack2(f2bf(silu_f(v1.z)), f2bf(silu_f(v1.w)));
            *(uint4*)(out + t * 8) = pk;
        }
#pragma unroll
        for (int p = 0; p < 3; ++p) {
            int i = t + p * 256;
            float xv = sX[i];
            float bb[8];
            kan_bases(xv, bb);
            uint4 pk;
            pk.x = pack2(f2bf(bb[0]), f2bf(bb[1]));
            pk.y = pack2(f2bf(bb[2]), f2bf(bb[3]));
            pk.z = pack2(f2bf(bb[4]), f2bf(bb[5]));
            pk.w = pack2(f2bf(bb[6]), f2bf(bb[7]));
            *(uint4*)(out + H + (size_t)i * 8) = pk;
        }
    }
}

// ==== Layer 1: 256x192 8-phase bf16 GEMM, grid = 256 blocks = 1/CU ====
//
// M=16384, N=768, K=6912. Grid 64 rowT x 4 colT = 256 blocks, 512 thr (8 waves, 2Mx4N).
// Per-wave per quadrant(128x64): 4 im x 1 n slice. A-frags for BOTH m-quadrants stay
// resident in regs (fA0/fA1, loaded once per K-step) -> 22 ds_read/K-step (minimal).
// Phases per K-step (buf X):
//   Pa: LDA0+LDB(B0) -> MM0(0) [8 mfma]   Pb: LDA1 -> MM1(0)
//   Pc: LDB(B1) -> MM1(1);MM0(1) [16]     Pd: LDB(B2) -> MM0(2);MM1(2)
// Region last reads: A0@Pa A1@Pb B0@Pa B1@Pc B2@Pd -> staggered frees.
// Stage plan (1 gload per STG_B, 2 per STG_A; issue order = loads 1..14/iter):
//   Pa: B2(buf1)<-2i+1 | Pb: A0(b0)<-2i+2 | Pc: A1(b0) | Pd: B0,B1(b0) |
//   Pe: B2(b0) | Pf: A0(b1)<-2i+3 | Pg: A1(b1) | Ph: B0,B1(b1)
// Counted vmcnt at phase ends: {10,10,11,8,-,10,11,8} (derived per-load; never 0 in
// loop; >=8 loads always in flight). Stage ks clamped to 107 at tail (race-free:
// stage-after-last-read holds for the clamped dup loads too).
// XCD swizzle: rowT=(b&7)*8+(s>>2), colT=s&3 -> 8x4 block sub-grid per XCD; the 4
// blocks sharing a rowT are same-XCD so the A K-stripe (256KB) is L2-resident.

#define AS1 __attribute__((address_space(1)))
#define AS3 __attribute__((address_space(3)))

#define DSR(D, A, O) asm volatile("ds_read_b128 %0, %1 offset:" #O : "=v"(D) : "v"(A) : "memory")
#define LDA0(O) do{ DSR(fA0[0],avA[0],O); DSR(fA0[1],avA[1],O); DSR(fA0[2],avA[2],O); DSR(fA0[3],avA[3],O); \
                    DSR(fA0[4],avA[4],O); DSR(fA0[5],avA[5],O); DSR(fA0[6],avA[6],O); DSR(fA0[7],avA[7],O); }while(0)
#define LDA1(O) do{ DSR(fA1[0],avA[0],O); DSR(fA1[1],avA[1],O); DSR(fA1[2],avA[2],O); DSR(fA1[3],avA[3],O); \
                    DSR(fA1[4],avA[4],O); DSR(fA1[5],avA[5],O); DSR(fA1[6],avA[6],O); DSR(fA1[7],avA[7],O); }while(0)
#define LDB(O)  do{ DSR(fB[0],avB[0],O); DSR(fB[1],avB[1],O); }while(0)

#define MM0(QN) do{ \
    _Pragma("unroll") \
    for (int kk = 0; kk < 2; ++kk) \
        _Pragma("unroll") \
        for (int im = 0; im < 4; ++im) \
            acc0[QN][im] = __builtin_amdgcn_mfma_f32_16x16x32_bf16( \
                fA0[im*2+kk], fB[kk], acc0[QN][im], 0, 0, 0); \
}while(0)
#define MM1(QN) do{ \
    _Pragma("unroll") \
    for (int kk = 0; kk < 2; ++kk) \
        _Pragma("unroll") \
        for (int im = 0; im < 4; ++im) \
            acc1[QN][im] = __builtin_amdgcn_mfma_f32_16x16x32_bf16( \
                fA1[im*2+kk], fB[kk], acc1[QN][im], 0, 0, 0); \
}while(0)

#define STG_A(BF,HH,KS) do{ \
    __builtin_amdgcn_global_load_lds((const AS1 void*)(pA##HH[0] + (size_t)(KS)*64), \
        (AS3 void*)&sA[BF][HH][wb8], 16, 0, 0); \
    __builtin_amdgcn_global_load_lds((const AS1 void*)(pA##HH[1] + (size_t)(KS)*64), \
        (AS3 void*)&sA[BF][HH][4096 + wb8], 16, 0, 0); \
}while(0)
#define STG_B(BF,QN,KS) \
    __builtin_amdgcn_global_load_lds((const AS1 void*)(pB[QN] + (size_t)(KS)*64), \
        (AS3 void*)&sB[BF][QN][wb8], 16, 0, 0)

#define PH_MID do{ __builtin_amdgcn_s_barrier(); \
    asm volatile("s_waitcnt lgkmcnt(0)" ::: "memory"); \
    __builtin_amdgcn_sched_barrier(0); \
    __builtin_amdgcn_s_setprio(1); }while(0)
#define PH_END do{ __builtin_amdgcn_s_setprio(0); \
    __builtin_amdgcn_sched_barrier(0); \
    __builtin_amdgcn_s_barrier(); }while(0)
#define PH_END_VMN(N) do{ __builtin_amdgcn_s_setprio(0); \
    __builtin_amdgcn_sched_barrier(0); \
    asm volatile("s_waitcnt vmcnt(" #N ")" ::: "memory"); \
    __builtin_amdgcn_s_barrier(); }while(0)

__global__ __launch_bounds__(512, 2) void kan1_gemm(
    const unsigned short* __restrict__ F, const unsigned short* __restrict__ wp,
    unsigned short* __restrict__ l1)
{
    __shared__ __align__(16) unsigned short sA[2][2][8192];  // [buf][half 128rows][128*64]
    __shared__ __align__(16) unsigned short sB[2][3][4096];  // [buf][third 64rows][64*64]

    const int b = blockIdx.x;                  // 0..255
    const int s = b >> 3;
    const int rowT = (b & 7) * 8 + (s >> 2);   // 0..63
    const int colT = s & 3;                    // 0..3
    const int rowBase = rowT * 256, colBase = colT * 192;

    const int t = threadIdx.x;
    const int lane = t & 63;
    const int quad = lane >> 4, lm = lane & 15, p7 = lane & 7;
    const int wv = t >> 6, wr = wv & 1, wc = wv >> 1;   // 2M x 4N wave grid

    // staging geometry: thread t covers granule t of a region; row rr, slot XOR-swizzled
    const int rr = t >> 3;                    // 0..63
    const int slotx = (t & 7) ^ (rr & 7);
    const int wb8 = (t & 448) * 8;            // wave-uniform LDS elem base (wv*512)

    const unsigned short* pA0[2]; const unsigned short* pA1[2];
    const unsigned short* pB[3];
#pragma unroll
    for (int p = 0; p < 2; ++p) {
        pA0[p] = F + (size_t)(rowBase +       p*64 + rr) * KEXP + slotx*8;
        pA1[p] = F + (size_t)(rowBase + 128 + p*64 + rr) * KEXP + slotx*8;
    }
#pragma unroll
    for (int q = 0; q < 3; ++q)
        pB[q] = wp + (size_t)(colBase + q*64 + rr) * KEXP + slotx*8;

    // ds_read addresses (region-relative; buf/region picked via asm offset imm)
    // A offsets: buf*32768 + qm*16384; B offsets: buf*24576 + qn*8192
    unsigned int avA[8], avB[2];
    {
        unsigned int aB = (unsigned int)(size_t)(AS3 unsigned short*)&sA[0][0][0];
        unsigned int bB = (unsigned int)(size_t)(AS3 unsigned short*)&sB[0][0][0];
#pragma unroll
        for (int im = 0; im < 4; ++im)
#pragma unroll
            for (int kk = 0; kk < 2; ++kk)
                avA[im*2+kk] = aB + (unsigned)(((wr*64 + im*16 + lm)*64 + (((kk*4+quad)^p7)*8)) * 2);
#pragma unroll
        for (int kk = 0; kk < 2; ++kk)
            avB[kk] = bB + (unsigned)(((wc*16 + lm)*64 + (((kk*4+quad)^p7)*8)) * 2);
    }

    floatx4 acc0[3][4] = {};   // [qn][im], qm=0 rows
    floatx4 acc1[3][4] = {};   // qm=1 rows
    bhalf8 fA0[8], fA1[8], fB[2];

    // prologue: buf0 <- ks0 (7 loads), buf1 <- ks1 minus B2 (6 loads); retire first 5
    STG_A(0,0,0); STG_A(0,1,0); STG_B(0,0,0); STG_B(0,1,0); STG_B(0,2,0);
    STG_A(1,0,1); STG_A(1,1,1); STG_B(1,0,1); STG_B(1,1,1);
    asm volatile("s_waitcnt vmcnt(8)" ::: "memory");
    __builtin_amdgcn_s_barrier();

#pragma unroll 1
    for (int i = 0; i < NITER; ++i) {
        const int k1 = 2*i + 1;
        const int k2 = (2*i + 2 > 107) ? 107 : 2*i + 2;
        const int k3 = (2*i + 3 > 107) ? 107 : 2*i + 3;
        // K-step 2i from buf0
        LDA0(0);     LDB(0);     STG_B(1,2,k1);               PH_MID; MM0(0);         PH_END_VMN(10);
        LDA1(16384);             STG_A(0,0,k2);               PH_MID; MM1(0);         PH_END_VMN(10);
        LDB(8192);               STG_A(0,1,k2);               PH_MID; MM1(1); MM0(1); PH_END_VMN(11);
        LDB(16384);              STG_B(0,0,k2); STG_B(0,1,k2);PH_MID; MM0(2); MM1(2); PH_END_VMN(8);
        // K-step 2i+1 from buf1
        LDA0(32768); LDB(24576); STG_B(0,2,k2);               PH_MID; MM0(0);         PH_END;
        LDA1(49152);             STG_A(1,0,k3);               PH_MID; MM1(0);         PH_END_VMN(10);
        LDB(32768);              STG_A(1,1,k3);               PH_MID; MM1(1); MM0(1); PH_END_VMN(11);
        LDB(40960);              STG_B(1,0,k3); STG_B(1,1,k3);PH_MID; MM0(2); MM1(2); PH_END_VMN(8);
    }

    // epilogue: C layout col=lane&15, row=quad*4+reg
#pragma unroll
    for (int qn = 0; qn < 3; ++qn)
#pragma unroll
    for (int im = 0; im < 4; ++im) {
        const int col = colBase + qn*64 + wc*16 + lm;
        {
            const int row0 = rowBase + wr*64 + im*16 + quad*4;
#pragma unroll
            for (int rg = 0; rg < 4; ++rg)
                l1[(size_t)(row0 + rg) * H + col] = f2bf(acc0[qn][im][rg]);
        }
        {
            const int row0 = rowBase + 128 + wr*64 + im*16 + quad*4;
#pragma unroll
            for (int rg = 0; rg < 4; ++rg)
                l1[(size_t)(row0 + rg) * H + col] = f2bf(acc1[qn][im][rg]);
        }
    }
}

// ---- Layer 2: unchanged (R5 shape: 4 rows/block, wave per row)
__global__ __launch_bounds__(256) void kan2_kernel(
    const unsigned short* __restrict__ l1, const float* __restrict__ bw,
    const float* __restrict__ sw, const float* __restrict__ sc,
    float* __restrict__ out)
{
    const int lane = threadIdx.x & 63;
    const int wv = threadIdx.x >> 6;
    const int n = blockIdx.x * 4 + wv;
    float a0 = 0.f, a1 = 0.f;
#pragma unroll
    for (int ii = 0; ii < H / 64; ++ii) {
        int i = lane + ii * 64;
        float h = bf2f(l1[(size_t)n * H + i]);
        float u = gelu_fast(h);
        float f0 = silu_f(u);
        float bb[8];
        kan_bases(u, bb);
        float bw0 = bw[i], bw1 = bw[H + i];
        float s0 = sc[i], s1 = sc[H + i];
        const float4* q0 = (const float4*)(sw + (size_t)i * 8);
        const float4* q1 = (const float4*)(sw + (size_t)(H + i) * 8);
        float4 w00 = q0[0], w01 = q0[1];
        float4 w10 = q1[0], w11 = q1[1];
        float t0 = bb[0]*w00.x + bb[1]*w00.y + bb[2]*w00.z + bb[3]*w00.w
                 + bb[4]*w01.x + bb[5]*w01.y + bb[6]*w01.z + bb[7]*w01.w;
        float t1 = bb[0]*w10.x + bb[1]*w10.y + bb[2]*w10.z + bb[3]*w10.w
                 + bb[4]*w11.x + bb[5]*w11.y + bb[6]*w11.z + bb[7]*w11.w;
        a0 += f0 * bw0 + s0 * t0;
        a1 += f0 * bw1 + s1 * t1;
    }
#pragma unroll
    for (int off = 32; off > 0; off >>= 1) {
        a0 += __shfl_down(a0, off, 64);
        a1 += __shfl_down(a1, off, 64);
    }
    if (lane == 0) {
        out[(size_t)n * 2 + 0] = a0;
        out[(size_t)n * 2 + 1] = a1;
    }
}

extern "C" void kernel_launch(void* const* d_in, const int* in_sizes, int n_in,
                              void* d_out, int out_size, void* d_ws, size_t ws_size,
                              hipStream_t stream) {
    const float* hidden = (const float*)d_in[0];
    const float* bw1    = (const float*)d_in[1];
    const float* sw1    = (const float*)d_in[2];
    const float* sc1    = (const float*)d_in[3];
    const float* bw2    = (const float*)d_in[4];
    const float* sw2    = (const float*)d_in[5];
    const float* sc2    = (const float*)d_in[6];
    float* out = (float*)d_out;

    const size_t l1_elems = (size_t)NROWS * H;     // 25.2 MB bf16
    const size_t wp_elems = (size_t)H * KEXP;      // 10.6 MB bf16
    unsigned short* l1 = (unsigned short*)d_ws;
    unsigned short* wp = l1 + l1_elems;
    unsigned short* F  = wp + wp_elems;            // 226.5 MB bf16

    prep_expand<<<H + NROWS, 256, 0, stream>>>(hidden, bw1, sw1, sc1, wp, F);
    kan1_gemm<<<256, 512, 0, stream>>>(F, wp, l1);
    kan2_kernel<<<NROWS / 4, 256, 0, stream>>>(l1, bw2, sw2, sc2, out);
}